// Round 3
// baseline (551.652 us; speedup 1.0000x reference)
//
#include <hip/hip_runtime.h>
#include <hip/hip_bf16.h>

typedef __bf16 bf16x8 __attribute__((ext_vector_type(8)));
typedef float f32x4 __attribute__((ext_vector_type(4)));

#define NROWS 100000
#define EPS 1e-5f
#define SLOPE 0.2f

// ---------------- GEMM: Y = LeakyReLU(A @ W^T + bias), plus column sum/sumsq ----
// A: [M,K] row-major (bf16, or fp32 converted inline when F32IN);
// W: [Ncols,K] row-major (same dtype rule); bias: [Ncols] f32.
// Y: [M,Ncols] bf16 — NO aliasing with A allowed (two column-blocks share A rows).
// sum/sumsq: [Ncols] f32 atomics.
// Tile 128x128, BK=64, 4 waves (2x2), each wave 64x64 via 4x4 MFMA 16x16x32.
constexpr int BM = 128, BN = 128, BK = 64;
constexpr int LDSP = BK + 8;  // padded row: 144B stride -> conflict-free b128

template <bool F32IN>
__global__ __launch_bounds__(256, 2)
void gemm_bn(const __bf16* __restrict__ A, const float* __restrict__ A32,
             const __bf16* __restrict__ W, const float* __restrict__ W32,
             const float* __restrict__ bias, __bf16* __restrict__ Y,
             float* __restrict__ sum, float* __restrict__ sumsq,
             int M, int K, int Ncols)
{
    __shared__ __bf16 sA[BM * LDSP];
    __shared__ __bf16 sB[BN * LDSP];

    const int tid  = threadIdx.x;
    const int wave = tid >> 6, lane = tid & 63;
    const int wm = wave & 1, wn = wave >> 1;
    const int quad = lane >> 4, l16 = lane & 15;
    const int rowBase = blockIdx.x * BM;
    const int colBase = blockIdx.y * BN;

    f32x4 acc[4][4] = {};

    for (int kk = 0; kk < K; kk += BK) {
        #pragma unroll
        for (int p = 0; p < 4; ++p) {
            int r = p * 32 + (tid >> 3);
            int c = (tid & 7) * 8;
            int gr = rowBase + r;
            int wr = colBase + r;
            bf16x8 va = {}, vb = {};
            if constexpr (F32IN) {
                if (gr < M) {
                    const float* s = A32 + (size_t)gr * K + kk + c;
                    float4 x0 = *(const float4*)s, x1 = *(const float4*)(s + 4);
                    va[0]=(__bf16)x0.x; va[1]=(__bf16)x0.y; va[2]=(__bf16)x0.z; va[3]=(__bf16)x0.w;
                    va[4]=(__bf16)x1.x; va[5]=(__bf16)x1.y; va[6]=(__bf16)x1.z; va[7]=(__bf16)x1.w;
                }
                if (wr < Ncols) {
                    const float* s = W32 + (size_t)wr * K + kk + c;
                    float4 x0 = *(const float4*)s, x1 = *(const float4*)(s + 4);
                    vb[0]=(__bf16)x0.x; vb[1]=(__bf16)x0.y; vb[2]=(__bf16)x0.z; vb[3]=(__bf16)x0.w;
                    vb[4]=(__bf16)x1.x; vb[5]=(__bf16)x1.y; vb[6]=(__bf16)x1.z; vb[7]=(__bf16)x1.w;
                }
            } else {
                if (gr < M) va = *(const bf16x8*)(A + (size_t)gr * K + kk + c);
                if (wr < Ncols) vb = *(const bf16x8*)(W + (size_t)wr * K + kk + c);
            }
            *(bf16x8*)(&sA[r * LDSP + c]) = va;
            *(bf16x8*)(&sB[r * LDSP + c]) = vb;
        }
        __syncthreads();

        #pragma unroll
        for (int ks = 0; ks < BK; ks += 32) {
            bf16x8 af[4], bfr[4];
            #pragma unroll
            for (int mi = 0; mi < 4; ++mi)
                af[mi] = *(const bf16x8*)(&sA[(wm * 64 + mi * 16 + l16) * LDSP + ks + quad * 8]);
            #pragma unroll
            for (int ni = 0; ni < 4; ++ni)
                bfr[ni] = *(const bf16x8*)(&sB[(wn * 64 + ni * 16 + l16) * LDSP + ks + quad * 8]);
            #pragma unroll
            for (int mi = 0; mi < 4; ++mi)
                #pragma unroll
                for (int ni = 0; ni < 4; ++ni)
                    acc[mi][ni] = __builtin_amdgcn_mfma_f32_16x16x32_bf16(
                        af[mi], bfr[ni], acc[mi][ni], 0, 0, 0);
        }
        __syncthreads();
    }

    // epilogue: bias + LeakyReLU, store bf16, accumulate column stats (fp32)
    float csum[4] = {0.f, 0.f, 0.f, 0.f};
    float csq[4]  = {0.f, 0.f, 0.f, 0.f};
    #pragma unroll
    for (int mi = 0; mi < 4; ++mi) {
        int r0 = rowBase + wm * 64 + mi * 16 + quad * 4;
        #pragma unroll
        for (int ni = 0; ni < 4; ++ni) {
            int col = colBase + wn * 64 + ni * 16 + l16;
            float bcol = bias[col];
            #pragma unroll
            for (int r = 0; r < 4; ++r) {
                int row = r0 + r;
                if (row < M) {
                    float y = acc[mi][ni][r] + bcol;
                    y = (y > 0.f) ? y : SLOPE * y;
                    Y[(size_t)row * Ncols + col] = (__bf16)y;
                    csum[ni] += y;
                    csq[ni]  += y * y;
                }
            }
        }
    }
    #pragma unroll
    for (int ni = 0; ni < 4; ++ni) {
        float s = csum[ni], q = csq[ni];
        s += __shfl_xor(s, 16); s += __shfl_xor(s, 32);
        q += __shfl_xor(q, 16); q += __shfl_xor(q, 32);
        if (quad == 0) {
            int col = colBase + wn * 64 + ni * 16 + l16;
            atomicAdd(&sum[col], s);
            atomicAdd(&sumsq[col], q);
        }
    }
}

// ------------- stats: s = g*rsqrt(var+eps), t = beta - mean*s --------------------
__global__ void stats_k(const float* __restrict__ sum, const float* __restrict__ sumsq,
                        const float* __restrict__ g, const float* __restrict__ beta,
                        float* __restrict__ s, float* __restrict__ t,
                        int Ncols, float invN)
{
    int c = blockIdx.x * blockDim.x + threadIdx.x;
    if (c < Ncols) {
        float m = sum[c] * invN;
        float v = sumsq[c] * invN - m * m;
        float sc = g[c] * rsqrtf(v + EPS);
        s[c] = sc;
        t[c] = beta[c] - m * sc;
    }
}

// ------------- fold BN into next layer: W' = W*diag(s) (bf16), b' = b + W@t ------
__global__ void fold_k(const float* __restrict__ W, const float* __restrict__ b,
                       const float* __restrict__ s, const float* __restrict__ t,
                       __bf16* __restrict__ Wf, float* __restrict__ bf_, int K)
{
    int n = blockIdx.x;
    int lane = threadIdx.x;  // 64
    float dot = 0.f;
    for (int k = lane; k < K; k += 64) {
        float w = W[(size_t)n * K + k];
        Wf[(size_t)n * K + k] = (__bf16)(w * s[k]);
        dot += w * t[k];
    }
    #pragma unroll
    for (int off = 32; off; off >>= 1) dot += __shfl_down(dot, off);
    if (lane == 0) bf_[n] = b[n] + dot;
}

// ------------- final BN: F = Y3*s + t (fp32, straight into d_out) ----------------
__global__ void bn_apply(const __bf16* __restrict__ Y, const float* __restrict__ s,
                         const float* __restrict__ t, float* __restrict__ F, long n8)
{
    long i = blockIdx.x * (long)blockDim.x + threadIdx.x;
    if (i >= n8) return;
    bf16x8 v = *(const bf16x8*)(Y + i * 8);
    int c0 = (int)((i * 8) & 127);
    float4 f0, f1;
    f0.x = (float)v[0] * s[c0 + 0] + t[c0 + 0];
    f0.y = (float)v[1] * s[c0 + 1] + t[c0 + 1];
    f0.z = (float)v[2] * s[c0 + 2] + t[c0 + 2];
    f0.w = (float)v[3] * s[c0 + 3] + t[c0 + 3];
    f1.x = (float)v[4] * s[c0 + 4] + t[c0 + 4];
    f1.y = (float)v[5] * s[c0 + 5] + t[c0 + 5];
    f1.z = (float)v[6] * s[c0 + 6] + t[c0 + 6];
    f1.w = (float)v[7] * s[c0 + 7] + t[c0 + 7];
    *(float4*)(F + i * 8) = f0;
    *(float4*)(F + i * 8 + 4) = f1;
}

// ------------- neighbor mean gather: out[i] = mean_k F[idx[i*16+k]] (fp32) -------
__global__ __launch_bounds__(256)
void gather_mean(const float* __restrict__ F, const int* __restrict__ idx,
                 float* __restrict__ out, int N)
{
    int row = blockIdx.x * 4 + (threadIdx.x >> 6);  // one row per wave
    if (row >= N) return;
    int lane = threadIdx.x & 63;
    const int* ib = idx + (size_t)row * 16;
    float a0 = 0.f, a1 = 0.f;
    #pragma unroll
    for (int k = 0; k < 16; ++k) {
        int j = ib[k];  // wave-uniform -> scalar load
        float2 v = *(const float2*)(F + (size_t)j * 128 + lane * 2);
        a0 += v.x;
        a1 += v.y;
    }
    float2 o;
    o.x = a0 * 0.0625f;
    o.y = a1 * 0.0625f;
    *(float2*)(out + (size_t)row * 128 + lane * 2) = o;
}

extern "C" void kernel_launch(void* const* d_in, const int* in_sizes, int n_in,
                              void* d_out, int out_size, void* d_ws, size_t ws_size,
                              hipStream_t stream)
{
    const float* X   = (const float*)d_in[0];
    const int*   idx = (const int*)d_in[1];
    // d_in[2] = prob_retained (unused, ==1)
    const float* W1  = (const float*)d_in[3];
    const float* b1  = (const float*)d_in[4];
    const float* g1  = (const float*)d_in[5];
    const float* be1 = (const float*)d_in[6];
    const float* W2  = (const float*)d_in[7];
    const float* b2  = (const float*)d_in[8];
    const float* g2  = (const float*)d_in[9];
    const float* be2 = (const float*)d_in[10];
    const float* W3  = (const float*)d_in[11];
    const float* b3  = (const float*)d_in[12];
    const float* g3  = (const float*)d_in[13];
    const float* be3 = (const float*)d_in[14];

    char* ws = (char*)d_ws;
    float* sum1 = (float*)(ws + 0);
    float* sq1  = (float*)(ws + 1024);
    float* sum2 = (float*)(ws + 2048);
    float* sq2  = (float*)(ws + 3072);
    float* sum3 = (float*)(ws + 4096);
    float* sq3  = (float*)(ws + 4608);
    float* s1   = (float*)(ws + 5120);
    float* t1   = (float*)(ws + 6144);
    float* s2   = (float*)(ws + 7168);
    float* t2   = (float*)(ws + 8192);
    float* s3   = (float*)(ws + 9216);
    float* t3   = (float*)(ws + 9728);
    float* b2f  = (float*)(ws + 10240);
    float* b3f  = (float*)(ws + 11264);
    __bf16* W2f = (__bf16*)(ws + 13312);            // 256*256*2 = 131072 B
    __bf16* W3f = (__bf16*)(ws + 144384);           // 128*256*2 = 65536 B
    __bf16* Y1  = (__bf16*)(ws + (1 << 20));                   // [N,256] bf16 51.2 MB
    __bf16* Y2  = (__bf16*)(ws + (1 << 20) + 51200000);        // [N,256] bf16 51.2 MB
    __bf16* Y3  = Y1;  // [N,128] bf16; Y1 is dead after gemm2 (gemm3 reads only Y2)

    float* out_nu = (float*)d_out;                  // node_update [N,128] fp32
    float* F      = out_nu + (size_t)NROWS * 128;   // f [N,128] fp32

    const float invN = 1.0f / (float)NROWS;
    const dim3 blk(256);

    hipMemsetAsync(d_ws, 0, 5120, stream);  // zero sum/sumsq accumulators

    // layer 1: X[100000,128] @ W1[256,128]^T  (fp32 inputs converted inline)
    gemm_bn<true><<<dim3(782, 2), blk, 0, stream>>>(
        nullptr, X, nullptr, W1, b1, Y1, sum1, sq1, NROWS, 128, 256);
    stats_k<<<1, 256, 0, stream>>>(sum1, sq1, g1, be1, s1, t1, 256, invN);
    fold_k<<<256, 64, 0, stream>>>(W2, b2, s1, t1, W2f, b2f, 256);

    // layer 2: Y1[100000,256] @ W2'[256,256]^T -> Y2 (separate buffer: no race)
    gemm_bn<false><<<dim3(782, 2), blk, 0, stream>>>(
        Y1, nullptr, W2f, nullptr, b2f, Y2, sum2, sq2, NROWS, 256, 256);
    stats_k<<<1, 256, 0, stream>>>(sum2, sq2, g2, be2, s2, t2, 256, invN);
    fold_k<<<128, 64, 0, stream>>>(W3, b3, s2, t2, W3f, b3f, 256);

    // layer 3: Y2[100000,256] @ W3'[128,256]^T -> raw Y3 (pre-BN) into Y1 region
    gemm_bn<false><<<dim3(782, 1), blk, 0, stream>>>(
        Y2, nullptr, W3f, nullptr, b3f, Y3, sum3, sq3, NROWS, 256, 128);
    stats_k<<<1, 128, 0, stream>>>(sum3, sq3, g3, be3, s3, t3, 128, invN);

    // finalize f = Y3*s3 + t3 -> fp32 F (second half of d_out), then neighbor mean
    bn_apply<<<6250, 256, 0, stream>>>(Y3, s3, t3, F, (long)NROWS * 128 / 8);
    gather_mean<<<25000, 256, 0, stream>>>(F, idx, out_nu, NROWS);
}

// Round 4
// 365.478 us; speedup vs baseline: 1.5094x; 1.5094x over previous
//
#include <hip/hip_runtime.h>
#include <hip/hip_bf16.h>

typedef __bf16 bf16x8 __attribute__((ext_vector_type(8)));
typedef __bf16 bf16x2 __attribute__((ext_vector_type(2)));
typedef float f32x4 __attribute__((ext_vector_type(4)));

#define NROWS 100000
#define NSTRIPS 6250   // 100000 / 16, exact
#define EPS 1e-5f
#define SLOPE 0.2f

__device__ __forceinline__ bf16x8 cvt8(const float* s) {
    float4 x0 = *(const float4*)s, x1 = *(const float4*)(s + 4);
    bf16x8 o;
    o[0] = (__bf16)x0.x; o[1] = (__bf16)x0.y; o[2] = (__bf16)x0.z; o[3] = (__bf16)x0.w;
    o[4] = (__bf16)x1.x; o[5] = (__bf16)x1.y; o[6] = (__bf16)x1.z; o[7] = (__bf16)x1.w;
    return o;
}

// ---- streaming GEMM: Y = LeakyReLU(A @ W^T + bias), + column sum/sumsq --------
// Tall-skinny shape (M=100000, K<=256, N<=256): W-fragments live entirely in
// registers (per wave: NI*16 columns x full K). A streams from global straight
// into MFMA A-fragments. NO LDS, NO barriers. 4 waves/block share each 16-row
// strip (HBM fetch once, L1 serves the other 3).
// A-frag: lane reads A[row0+l16][ks*32+quad*8 ..+8] (16B, 64B/row granularity).
// C/D: col = l16, row = quad*4 + reg.
template <int KT, int NI, bool F32IN>
__global__ __launch_bounds__(256, 2)
void gemm_stream(const __bf16* __restrict__ A, const float* __restrict__ A32,
                 const __bf16* __restrict__ W, const float* __restrict__ W32,
                 const float* __restrict__ bias, __bf16* __restrict__ Y,
                 float* __restrict__ sum, float* __restrict__ sumsq)
{
    constexpr int KS = KT / 32;
    constexpr int NCOLS = NI * 64;           // 4 waves * NI*16 columns
    const int wave = threadIdx.x >> 6, lane = threadIdx.x & 63;
    const int quad = lane >> 4, l16 = lane & 15;
    const int c0 = wave * (NI * 16);

    // B-fragments for this wave's column slice, full K, in registers
    bf16x8 bfrag[NI][KS];
    float bcol[NI];
    #pragma unroll
    for (int ni = 0; ni < NI; ++ni) {
        int col = c0 + ni * 16 + l16;
        bcol[ni] = bias[col];
        #pragma unroll
        for (int ks = 0; ks < KS; ++ks) {
            int k = ks * 32 + quad * 8;
            if constexpr (F32IN) bfrag[ni][ks] = cvt8(W32 + (size_t)col * KT + k);
            else                 bfrag[ni][ks] = *(const bf16x8*)(W + (size_t)col * KT + k);
        }
    }

    float csum[NI] = {}, csq[NI] = {};

    for (int s = blockIdx.x; s < NSTRIPS; s += gridDim.x) {
        int row0 = s * 16;
        bf16x8 afrag[KS];
        #pragma unroll
        for (int ks = 0; ks < KS; ++ks) {
            int k = ks * 32 + quad * 8;
            if constexpr (F32IN) afrag[ks] = cvt8(A32 + (size_t)(row0 + l16) * KT + k);
            else                 afrag[ks] = *(const bf16x8*)(A + (size_t)(row0 + l16) * KT + k);
        }
        f32x4 acc[NI] = {};
        #pragma unroll
        for (int ks = 0; ks < KS; ++ks)
            #pragma unroll
            for (int ni = 0; ni < NI; ++ni)
                acc[ni] = __builtin_amdgcn_mfma_f32_16x16x32_bf16(
                    afrag[ks], bfrag[ni][ks], acc[ni], 0, 0, 0);

        #pragma unroll
        for (int ni = 0; ni < NI; ++ni) {
            int col = c0 + ni * 16 + l16;
            #pragma unroll
            for (int r = 0; r < 4; ++r) {
                float y = acc[ni][r] + bcol[ni];
                y = (y > 0.f) ? y : SLOPE * y;
                Y[(size_t)(row0 + quad * 4 + r) * NCOLS + col] = (__bf16)y;
                csum[ni] += y;
                csq[ni]  += y * y;
            }
        }
    }

    #pragma unroll
    for (int ni = 0; ni < NI; ++ni) {
        float s = csum[ni], q = csq[ni];
        s += __shfl_xor(s, 16); s += __shfl_xor(s, 32);
        q += __shfl_xor(q, 16); q += __shfl_xor(q, 32);
        if (quad == 0) {
            int col = c0 + ni * 16 + l16;
            atomicAdd(&sum[col], s);
            atomicAdd(&sumsq[col], q);
        }
    }
}

// ------------- stats: s = g*rsqrt(var+eps), t = beta - mean*s --------------------
__global__ void stats_k(const float* __restrict__ sum, const float* __restrict__ sumsq,
                        const float* __restrict__ g, const float* __restrict__ beta,
                        float* __restrict__ s, float* __restrict__ t,
                        int Ncols, float invN)
{
    int c = blockIdx.x * blockDim.x + threadIdx.x;
    if (c < Ncols) {
        float m = sum[c] * invN;
        float v = sumsq[c] * invN - m * m;
        float sc = g[c] * rsqrtf(v + EPS);
        s[c] = sc;
        t[c] = beta[c] - m * sc;
    }
}

// ------------- fold BN into next layer: W' = W*diag(s) (bf16), b' = b + W@t ------
__global__ void fold_k(const float* __restrict__ W, const float* __restrict__ b,
                       const float* __restrict__ s, const float* __restrict__ t,
                       __bf16* __restrict__ Wf, float* __restrict__ bf_, int K)
{
    int n = blockIdx.x;
    int lane = threadIdx.x;  // 64
    float dot = 0.f;
    for (int k = lane; k < K; k += 64) {
        float w = W[(size_t)n * K + k];
        Wf[(size_t)n * K + k] = (__bf16)(w * s[k]);
        dot += w * t[k];
    }
    #pragma unroll
    for (int off = 32; off; off >>= 1) dot += __shfl_down(dot, off);
    if (lane == 0) bf_[n] = b[n] + dot;
}

// ------------- final BN: F = Y3*s + t (fp32, straight into d_out) ----------------
__global__ void bn_apply(const __bf16* __restrict__ Y, const float* __restrict__ s,
                         const float* __restrict__ t, float* __restrict__ F, long n8)
{
    long i = blockIdx.x * (long)blockDim.x + threadIdx.x;
    if (i >= n8) return;
    bf16x8 v = *(const bf16x8*)(Y + i * 8);
    int c0 = (int)((i * 8) & 127);
    float4 f0, f1;
    f0.x = (float)v[0] * s[c0 + 0] + t[c0 + 0];
    f0.y = (float)v[1] * s[c0 + 1] + t[c0 + 1];
    f0.z = (float)v[2] * s[c0 + 2] + t[c0 + 2];
    f0.w = (float)v[3] * s[c0 + 3] + t[c0 + 3];
    f1.x = (float)v[4] * s[c0 + 4] + t[c0 + 4];
    f1.y = (float)v[5] * s[c0 + 5] + t[c0 + 5];
    f1.z = (float)v[6] * s[c0 + 6] + t[c0 + 6];
    f1.w = (float)v[7] * s[c0 + 7] + t[c0 + 7];
    *(float4*)(F + i * 8) = f0;
    *(float4*)(F + i * 8 + 4) = f1;
}

// ---- neighbor mean over bf16 pre-BN Y3, BN affine applied after the mean -------
// mean_k(s∘y3 + t) = s∘mean_k(y3) + t  (linear) — halves gathered read volume.
__global__ __launch_bounds__(256)
void gather_mean_bn(const __bf16* __restrict__ Y3, const int* __restrict__ idx,
                    const float* __restrict__ s3, const float* __restrict__ t3,
                    float* __restrict__ out, int N)
{
    int row = blockIdx.x * 4 + (threadIdx.x >> 6);  // one row per wave
    if (row >= N) return;
    int lane = threadIdx.x & 63;
    const int* ib = idx + (size_t)row * 16;
    float a0 = 0.f, a1 = 0.f;
    #pragma unroll
    for (int k = 0; k < 16; ++k) {
        int j = ib[k];  // wave-uniform -> scalar load
        bf16x2 v = *(const bf16x2*)(Y3 + (size_t)j * 128 + lane * 2);
        a0 += (float)v[0];
        a1 += (float)v[1];
    }
    float2 sc = *(const float2*)(s3 + lane * 2);
    float2 tc = *(const float2*)(t3 + lane * 2);
    float2 o;
    o.x = a0 * 0.0625f * sc.x + tc.x;
    o.y = a1 * 0.0625f * sc.y + tc.y;
    *(float2*)(out + (size_t)row * 128 + lane * 2) = o;
}

extern "C" void kernel_launch(void* const* d_in, const int* in_sizes, int n_in,
                              void* d_out, int out_size, void* d_ws, size_t ws_size,
                              hipStream_t stream)
{
    const float* X   = (const float*)d_in[0];
    const int*   idx = (const int*)d_in[1];
    // d_in[2] = prob_retained (unused, ==1)
    const float* W1  = (const float*)d_in[3];
    const float* b1  = (const float*)d_in[4];
    const float* g1  = (const float*)d_in[5];
    const float* be1 = (const float*)d_in[6];
    const float* W2  = (const float*)d_in[7];
    const float* b2  = (const float*)d_in[8];
    const float* g2  = (const float*)d_in[9];
    const float* be2 = (const float*)d_in[10];
    const float* W3  = (const float*)d_in[11];
    const float* b3  = (const float*)d_in[12];
    const float* g3  = (const float*)d_in[13];
    const float* be3 = (const float*)d_in[14];

    char* ws = (char*)d_ws;
    float* sum1 = (float*)(ws + 0);
    float* sq1  = (float*)(ws + 1024);
    float* sum2 = (float*)(ws + 2048);
    float* sq2  = (float*)(ws + 3072);
    float* sum3 = (float*)(ws + 4096);
    float* sq3  = (float*)(ws + 4608);
    float* s1   = (float*)(ws + 5120);
    float* t1   = (float*)(ws + 6144);
    float* s2   = (float*)(ws + 7168);
    float* t2   = (float*)(ws + 8192);
    float* s3   = (float*)(ws + 9216);
    float* t3   = (float*)(ws + 9728);
    float* b2f  = (float*)(ws + 10240);
    float* b3f  = (float*)(ws + 11264);
    __bf16* W2f = (__bf16*)(ws + 13312);            // 256*256*2 = 131072 B
    __bf16* W3f = (__bf16*)(ws + 144384);           // 128*256*2 = 65536 B
    __bf16* Y1  = (__bf16*)(ws + (1 << 20));                   // [N,256] bf16 51.2 MB
    __bf16* Y2  = (__bf16*)(ws + (1 << 20) + 51200000);        // [N,256] bf16 51.2 MB
    __bf16* Y3  = Y1;  // [N,128]; Y1 dead after gemm2 (gemm3 reads only Y2)

    float* out_nu = (float*)d_out;                  // node_update [N,128] fp32
    float* F      = out_nu + (size_t)NROWS * 128;   // f [N,128] fp32

    const float invN = 1.0f / (float)NROWS;
    const dim3 blk(256);
    const int GB = 512;  // 2 blocks/CU resident, block-strided strips

    hipMemsetAsync(d_ws, 0, 5120, stream);  // zero sum/sumsq accumulators

    // layer 1: X[100000,128] @ W1[256,128]^T (fp32 converted inline)
    gemm_stream<128, 4, true><<<GB, blk, 0, stream>>>(
        nullptr, X, nullptr, W1, b1, Y1, sum1, sq1);
    stats_k<<<1, 256, 0, stream>>>(sum1, sq1, g1, be1, s1, t1, 256, invN);
    fold_k<<<256, 64, 0, stream>>>(W2, b2, s1, t1, W2f, b2f, 256);

    // layer 2: Y1[100000,256] @ W2'[256,256]^T -> Y2
    gemm_stream<256, 4, false><<<GB, blk, 0, stream>>>(
        Y1, nullptr, W2f, nullptr, b2f, Y2, sum2, sq2);
    stats_k<<<1, 256, 0, stream>>>(sum2, sq2, g2, be2, s2, t2, 256, invN);
    fold_k<<<128, 64, 0, stream>>>(W3, b3, s2, t2, W3f, b3f, 256);

    // layer 3: Y2[100000,256] @ W3'[128,256]^T -> raw Y3 (pre-BN) into Y1 region
    gemm_stream<256, 2, false><<<GB, blk, 0, stream>>>(
        Y2, nullptr, W3f, nullptr, b3f, Y3, sum3, sq3);
    stats_k<<<1, 128, 0, stream>>>(sum3, sq3, g3, be3, s3, t3, 128, invN);

    // f = Y3*s3 + t3 -> fp32 F (second half of d_out); gather reads bf16 Y3
    bn_apply<<<6250, 256, 0, stream>>>(Y3, s3, t3, F, (long)NROWS * 128 / 8);
    gather_mean_bn<<<25000, 256, 0, stream>>>(Y3, idx, s3, t3, out_nu, NROWS);
}